// Round 10
// baseline (120.868 us; speedup 1.0000x reference)
//
#include <hip/hip_runtime.h>

// feature_seq (B=2, C=64, N=512) fp32. Window lengths [256, 1024, 512, 512].
// Output i is (B, N, C, L_i), concatenated flat in d_out.
// out[b][n][c][l] = (0 <= n - L/2 + l < N) ? in[b][c][n - L/2 + l] : 0
//
// R10: outputs 2 and 3 (both L=512) are IDENTICAL tensors -> load once,
// store twice. Per-block work doubled to 2048 float4 (8 iters x 256 thr).
// Hot path = R8's proven structure: zero-padded input copy in ws (768 KB,
// L2-resident) -> one unconditional dword-aligned vector load per output
// float4 -> nt store(s). No branches, no bounds checks in the main loop.

constexpr int B = 2;
constexpr int C = 64;   // log2 = 6
constexpr int N = 512;  // log2 = 9

constexpr int SZ256  = B * N * C * 256;   // 16,777,216 floats
constexpr int SZ1024 = B * N * C * 1024;  // 67,108,864
constexpr int SZ512  = B * N * C * 512;   // 33,554,432

// float4 counts per segment
constexpr int F256  = SZ256  / 4;   // 4,194,304
constexpr int F1024 = SZ1024 / 4;   // 16,777,216
constexpr int F512  = SZ512  / 4;   // 8,388,608

// 2048 float4 per block (8 iters x 256 threads)
constexpr int NB256  = F256  / 2048;  // 2048 blocks
constexpr int NB1024 = F1024 / 2048;  // 8192
constexpr int NB512  = F512  / 2048;  // 4096 (each writes out2 AND out3)
constexpr int NBLK = NB256 + NB1024 + NB512;  // 14336

constexpr int PROW = 1536;  // padded row: [512 zeros | 512 data | 512 zeros]

typedef float f32x4 __attribute__((ext_vector_type(4)));
typedef float f32x4u __attribute__((ext_vector_type(4), aligned(4)));

// 128 rows; 384 threads = one float4 slot each (slots 128..255 hold data).
__global__ __launch_bounds__(384)
void pad_kernel(const float* __restrict__ in, float* __restrict__ ws) {
    const int row = blockIdx.x;   // (b<<6)|c, 0..127
    const int p = threadIdx.x;    // float4 slot 0..383
    f32x4 v = {0.0f, 0.0f, 0.0f, 0.0f};
    if (p >= 128 && p < 256)
        v = *reinterpret_cast<const f32x4*>(in + (row << 9) + ((p - 128) << 2));
    *reinterpret_cast<f32x4*>(ws + row * PROW + (p << 2)) = v;
}

template <int L, bool DUP>
__device__ __forceinline__ void do_seg(const float* __restrict__ ws,
                                       float* __restrict__ out,
                                       float* __restrict__ out_dup,
                                       int blk, int tid) {
    constexpr int HALF = L / 2;
    constexpr int BIAS = 512 - HALF;      // padded offset of window start @n=0
    constexpr int L4 = L / 4;
    constexpr int L4_BITS = (L == 256) ? 6 : (L == 512) ? 7 : 8;
    constexpr int KS = 256 >> L4_BITS;    // rest step per k

    f32x4* __restrict__ out4 = reinterpret_cast<f32x4*>(out);
    f32x4* __restrict__ out4d = reinterpret_cast<f32x4*>(out_dup);

    const int lb    = (tid & (L4 - 1)) << 2;   // window-local element offset
    const int restT = tid >> L4_BITS;
    const int R0    = (blk * 2048) >> L4_BITS;

#pragma unroll
    for (int k = 0; k < 8; ++k) {
        int t    = blk * 2048 + k * 256 + tid;
        int rest = R0 + k * KS + restT;        // wave-uniform

        int c  = rest & (C - 1);
        int bb = rest >> 15;                   // rest / (N*C)
        int n  = (rest >> 6) & (N - 1);
        int r  = (bb << 6) | c;                // padded row index

        // single unconditional load: padding guarantees in-bounds, zeros OOB
        const float* __restrict__ src = ws + r * PROW + BIAS + n + lb;
        f32x4 v = *reinterpret_cast<const f32x4u*>(src);

        __builtin_nontemporal_store(v, out4 + t);
        if (DUP)
            __builtin_nontemporal_store(v, out4d + t);
    }
}

__global__ __launch_bounds__(256)
void msw_fused_kernel(const float* __restrict__ ws, float* __restrict__ out) {
    const int blk = blockIdx.x;
    const int tid = threadIdx.x;

    if (blk < NB256) {
        do_seg<256, false>(ws, out, nullptr, blk, tid);
    } else if (blk < NB256 + NB1024) {
        do_seg<1024, false>(ws, out + SZ256, nullptr, blk - NB256, tid);
    } else {
        // L=512: outputs 2 and 3 are identical — load once, store twice
        do_seg<512, true>(ws, out + SZ256 + SZ1024,
                          out + SZ256 + SZ1024 + SZ512,
                          blk - (NB256 + NB1024), tid);
    }
}

extern "C" void kernel_launch(void* const* d_in, const int* in_sizes, int n_in,
                              void* d_out, int out_size, void* d_ws, size_t ws_size,
                              hipStream_t stream) {
    const float* in = (const float*)d_in[0];
    float* out = (float*)d_out;
    float* ws = (float*)d_ws;   // needs B*C*PROW*4 = 786 KB scratch

    pad_kernel<<<B * C, 384, 0, stream>>>(in, ws);
    msw_fused_kernel<<<NBLK, 256, 0, stream>>>(ws, out);
}

// Round 11
// 114.294 us; speedup vs baseline: 1.0575x; 1.0575x over previous
//
#include <hip/hip_runtime.h>

// feature_seq (B=2, C=64, N=512) fp32. Window lengths [256, 1024, 512, 512].
// Output i is (B, N, C, L_i), concatenated flat in d_out.
// out[b][n][c][l] = (0 <= n - L/2 + l < N) ? in[b][c][n - L/2 + l] : 0
//
// FINAL (revert to R8, best measured 114.4 us = ~5.3 TB/s effective write).
// Structure: pre-kernel writes a zero-padded input copy to d_ws (per (b,c)
// row: [512 zeros | 512 data | 512 zeros], 768 KB total, L2-resident).
// Main kernel: one unconditional dword-aligned vector load per output
// float4 + one nt store. No branches, no bounds checks.
//
// Ablation history (all measured):
//  - 4x scalar loads / vector+branch / HW-bounds buffer gather: 118-126 us
//  - persistent blocks (16 tiles/block): 129 us (regressed)
//  - LDS-staged pure-store hot loop, plain stores: 114.4 us (== this)
//  - dup-store for identical L=512 outputs + 2048-f4 blocks: 120.9 us
// Conclusion: HBM-write-drain-limited; ~604 MB mandatory writes at
// ~7.3 TB/s steady + ~28 us fixed ramp. Kernel structure is not the limiter.

constexpr int B = 2;
constexpr int C = 64;   // log2 = 6
constexpr int N = 512;  // log2 = 9

constexpr int SZ256  = B * N * C * 256;   // 16,777,216 floats
constexpr int SZ1024 = B * N * C * 1024;  // 67,108,864
constexpr int SZ512  = B * N * C * 512;   // 33,554,432

constexpr int BLK256  = SZ256  / 4 / 1024;  // 4096 blocks
constexpr int BLK1024 = SZ1024 / 4 / 1024;  // 16384
constexpr int BLK512  = SZ512  / 4 / 1024;  // 8192
constexpr int NBLK = BLK256 + BLK1024 + 2 * BLK512;  // 36864

constexpr int PROW = 1536;  // padded row: [512 zeros | 512 data | 512 zeros]

typedef float f32x4 __attribute__((ext_vector_type(4)));
typedef float f32x4u __attribute__((ext_vector_type(4), aligned(4)));

// 128 rows; 384 threads = one float4 slot each (slots 128..255 hold data).
__global__ __launch_bounds__(384)
void pad_kernel(const float* __restrict__ in, float* __restrict__ ws) {
    const int row = blockIdx.x;   // (b<<6)|c, 0..127
    const int p = threadIdx.x;    // float4 slot 0..383
    f32x4 v = {0.0f, 0.0f, 0.0f, 0.0f};
    if (p >= 128 && p < 256)
        v = *reinterpret_cast<const f32x4*>(in + (row << 9) + ((p - 128) << 2));
    *reinterpret_cast<f32x4*>(ws + row * PROW + (p << 2)) = v;
}

template <int L>
__device__ __forceinline__ void do_seg(const float* __restrict__ ws,
                                       float* __restrict__ out,
                                       int blk, int tid) {
    constexpr int HALF = L / 2;
    constexpr int BIAS = 512 - HALF;      // padded offset of window start @n=0
    constexpr int L4 = L / 4;
    constexpr int L4_BITS = (L == 256) ? 6 : (L == 512) ? 7 : 8;
    constexpr int KS = 256 >> L4_BITS;    // rest step per k

    f32x4* __restrict__ out4 = reinterpret_cast<f32x4*>(out);

    const int lb    = (tid & (L4 - 1)) << 2;   // window-local element offset
    const int restT = tid >> L4_BITS;
    const int R0    = (blk * 1024) >> L4_BITS;

#pragma unroll
    for (int k = 0; k < 4; ++k) {
        int t    = blk * 1024 + k * 256 + tid;
        int rest = R0 + k * KS + restT;        // wave-uniform

        int c  = rest & (C - 1);
        int bb = rest >> 15;                   // rest / (N*C)
        int n  = (rest >> 6) & (N - 1);
        int r  = (bb << 6) | c;                // padded row index

        // single unconditional load: padding guarantees in-bounds, zeros OOB
        const float* __restrict__ src = ws + r * PROW + BIAS + n + lb;
        f32x4 v = *reinterpret_cast<const f32x4u*>(src);

        __builtin_nontemporal_store(v, out4 + t);
    }
}

__global__ __launch_bounds__(256)
void msw_fused_kernel(const float* __restrict__ ws, float* __restrict__ out) {
    const int blk = blockIdx.x;
    const int tid = threadIdx.x;

    if (blk < BLK256) {
        do_seg<256>(ws, out, blk, tid);
    } else if (blk < BLK256 + BLK1024) {
        do_seg<1024>(ws, out + SZ256, blk - BLK256, tid);
    } else if (blk < BLK256 + BLK1024 + BLK512) {
        do_seg<512>(ws, out + SZ256 + SZ1024, blk - (BLK256 + BLK1024), tid);
    } else {
        do_seg<512>(ws, out + SZ256 + SZ1024 + SZ512,
                    blk - (BLK256 + BLK1024 + BLK512), tid);
    }
}

extern "C" void kernel_launch(void* const* d_in, const int* in_sizes, int n_in,
                              void* d_out, int out_size, void* d_ws, size_t ws_size,
                              hipStream_t stream) {
    const float* in = (const float*)d_in[0];
    float* out = (float*)d_out;
    float* ws = (float*)d_ws;   // needs B*C*PROW*4 = 786 KB scratch

    pad_kernel<<<B * C, 384, 0, stream>>>(in, ws);
    msw_fused_kernel<<<NBLK, 256, 0, stream>>>(ws, out);
}